// Round 2
// baseline (544.246 us; speedup 1.0000x reference)
//
#include <hip/hip_runtime.h>
#include <hip/hip_bf16.h>
#include <cstdio>

typedef unsigned short u16;
typedef __attribute__((ext_vector_type(4))) float f32x4;
typedef __attribute__((ext_vector_type(8))) short s16x8;

__device__ __forceinline__ u16 bf16b(float f) {
  union { float f; unsigned u; } c; c.f = f;
  unsigned u = c.u;
  return (u16)((u + 0x7FFFu + ((u >> 16) & 1u)) >> 16);
}

__device__ __forceinline__ void load16(const void* g, void* l) {
  __builtin_amdgcn_global_load_lds(
      (const __attribute__((address_space(1))) void*)g,
      (__attribute__((address_space(3))) void*)l, 16, 0, 0);
}

// ---------------- converters ----------------

__global__ __launch_bounds__(256) void cvt_x_k(const float* __restrict__ x,
                                               u16* __restrict__ xb) {
  long i = ((long)blockIdx.x * 256 + threadIdx.x) * 4;
  float4 f = *(const float4*)&x[i];
  unsigned lo = (unsigned)bf16b(f.x) | ((unsigned)bf16b(f.y) << 16);
  unsigned hi = (unsigned)bf16b(f.z) | ((unsigned)bf16b(f.w) << 16);
  uint2 v; v.x = lo; v.y = hi;
  *(uint2*)&xb[i] = v;
}

// Wcat[n][k], n<64: Wq^T, 64<=n<128: Wk^T, else Wv^T  (row-major [640][512])
__global__ __launch_bounds__(256) void cvt_w_k(const float* __restrict__ Wq,
                                               const float* __restrict__ Wk,
                                               const float* __restrict__ Wv,
                                               u16* __restrict__ Wcat) {
  int idx = blockIdx.x * 256 + threadIdx.x;  // 640*512
  int nn = idx >> 9, k = idx & 511;
  float v;
  if (nn < 64)       v = Wq[k * 64 + nn];
  else if (nn < 128) v = Wk[k * 64 + (nn - 64)];
  else               v = Wv[k * 512 + (nn - 128)];
  Wcat[idx] = bf16b(v);
}

// Vr [b][4096][512] -> Vt [b][512][4096]
__global__ __launch_bounds__(256) void transV_k(const u16* __restrict__ Vr,
                                                u16* __restrict__ Vt) {
  __shared__ u16 t[64][66];
  const int b = blockIdx.z;
  const long i0 = (long)blockIdx.x * 64, c0 = (long)blockIdx.y * 64;
  const u16* src = Vr + (long)b * 4096 * 512;
  u16* dst = Vt + (long)b * 512 * 4096;
  const int tid = threadIdx.x;
#pragma unroll
  for (int p = 0; p < 16; ++p) {
    int idx = p * 256 + tid;
    int r = idx >> 6, c = idx & 63;
    t[r][c] = src[(i0 + r) * 512 + c0 + c];
  }
  __syncthreads();
#pragma unroll
  for (int p = 0; p < 16; ++p) {
    int idx = p * 256 + tid;
    int r = idx >> 6, c = idx & 63;
    dst[(c0 + r) * 4096 + i0 + c] = t[c][r];
  }
}

// ---------------- generic GEMM-T: C[m,n] = sum_k A[m,k]*B[n,k] ----------------
// A:[M][K] row-major bf16 (lda), B:[N][K] row-major bf16 (ldb). BK=64.
// 4 waves in 2x2; wave tile (BM/2 x BN/2); 16x16x32 bf16 MFMA.
// EPI 0: proj -> Qb/Kb/Vr bf16 + bias   (p0,p1,p2 dsts; p3,p4,p5 biases)
// EPI 1: P = exp(acc - mfin[n]) * linv[n] -> bf16 p0 (ld 4096); p1=mfin p2=linv
// EPI 2: out = gamma*acc + x  (p0=out, p1=x, p2=gamma; ld 512)
template <int BM, int BN, int EPI>
__global__ __launch_bounds__(256, 2) void gemmT(
    const u16* __restrict__ A, const u16* __restrict__ B, int K, int lda,
    int ldb, long sA, long sB, void* p0, void* p1, void* p2, void* p3,
    void* p4, void* p5, long s0, long s1, long s2) {
  constexpr int FM = BM / 32, FN = BN / 32;
  __shared__ __align__(16) u16 At[BM * 64];
  __shared__ __align__(16) u16 Bt[BN * 64];
  const int tid = threadIdx.x;
  const int lane = tid & 63, w = tid >> 6;
  const int wr = w >> 1, wc = w & 1;
  const int l15 = lane & 15, lhi = lane >> 4;
  const long m0 = (long)blockIdx.x * BM;
  const long n0 = (long)blockIdx.y * BN;
  const int z = blockIdx.z;
  A += (long)z * sA;
  B += (long)z * sB;
  char* b0 = (char*)p0 + (long)z * s0;
  char* b1 = (char*)p1 + (long)z * s1;
  char* b2 = (char*)p2 + (long)z * s2;

  f32x4 acc[FM][FN] = {};

  for (int k0 = 0; k0 < K; k0 += 64) {
#pragma unroll
    for (int it = 0; it < (BM + BN) * 8 / 256; ++it) {
      int q = it * 256 + tid;
      if (q < BM * 8) {
        int row = q >> 3, c8 = q & 7;
        load16(A + (m0 + row) * lda + k0 + c8 * 8, &At[q * 8]);
      } else {
        int q2 = q - BM * 8;
        int row = q2 >> 3, c8 = q2 & 7;
        load16(B + (n0 + row) * ldb + k0 + c8 * 8, &Bt[q2 * 8]);
      }
    }
    __syncthreads();
#pragma unroll
    for (int kk = 0; kk < 64; kk += 32) {
      s16x8 af[FM], bf[FN];
#pragma unroll
      for (int i = 0; i < FM; ++i)
        af[i] = *(const s16x8*)&At[(wr * (BM / 2) + i * 16 + l15) * 64 + kk + lhi * 8];
#pragma unroll
      for (int j = 0; j < FN; ++j)
        bf[j] = *(const s16x8*)&Bt[(wc * (BN / 2) + j * 16 + l15) * 64 + kk + lhi * 8];
#pragma unroll
      for (int i = 0; i < FM; ++i)
#pragma unroll
        for (int j = 0; j < FN; ++j)
          acc[i][j] = __builtin_amdgcn_mfma_f32_16x16x32_bf16(af[i], bf[j],
                                                              acc[i][j], 0, 0, 0);
    }
    __syncthreads();
  }

  float gma = 0.f;
  if constexpr (EPI == 2) gma = ((const float*)b2)[0];

#pragma unroll
  for (int i = 0; i < FM; ++i) {
#pragma unroll
    for (int j = 0; j < FN; ++j) {
      long mm = m0 + wr * (BM / 2) + i * 16 + lhi * 4;
      long nn = n0 + wc * (BN / 2) + j * 16 + l15;
#pragma unroll
      for (int r = 0; r < 4; ++r) {
        long m = mm + r;
        float v = acc[i][j][r];
        if constexpr (EPI == 0) {
          if (nn < 64) {
            v += ((const float*)p3)[nn];
            ((u16*)b0)[m * 64 + nn] = bf16b(v);
          } else if (nn < 128) {
            v += ((const float*)p4)[nn - 64];
            ((u16*)b1)[m * 64 + nn - 64] = bf16b(v);
          } else {
            v += ((const float*)p5)[nn - 128];
            ((u16*)b2)[m * 512 + nn - 128] = bf16b(v);
          }
        } else if constexpr (EPI == 1) {
          float e = __expf(v - ((const float*)b1)[nn]) * ((const float*)b2)[nn];
          ((u16*)b0)[m * 4096 + nn] = bf16b(e);
        } else {
          float xv = ((const float*)b1)[m * 512 + nn];
          ((float*)b0)[m * 512 + nn] = gma * v + xv;
        }
      }
    }
  }
}

// ---------------- softmax row stats (over j) via S recompute ----------------
// grid (32 i-tiles, 4 j-chunks, 8 batches); each WG: 128 i rows x 1024 j
__global__ __launch_bounds__(256, 2) void stats_k(const u16* __restrict__ Qb,
                                                  const u16* __restrict__ Kb,
                                                  float* __restrict__ m_part,
                                                  float* __restrict__ l_part) {
  const int b = blockIdx.z, jc = blockIdx.y;
  const long i0 = (long)blockIdx.x * 128;
  const u16* Q = Qb + (long)b * 4096 * 64;
  const u16* Kp = Kb + (long)b * 4096 * 64;
  __shared__ __align__(16) u16 Qt[128 * 64];
  __shared__ __align__(16) u16 Kt[128 * 64];
  const int tid = threadIdx.x, lane = tid & 63, w = tid >> 6;
  const int l15 = lane & 15, lhi = lane >> 4;

#pragma unroll
  for (int it = 0; it < 4; ++it) {
    int q = it * 256 + tid;
    int row = q >> 3, c8 = q & 7;
    load16(Q + (i0 + row) * 64 + c8 * 8, &Qt[q * 8]);
  }

  float mrun[2][4], lrun[2][4];
#pragma unroll
  for (int i = 0; i < 2; ++i)
#pragma unroll
    for (int r = 0; r < 4; ++r) { mrun[i][r] = -1e30f; lrun[i][r] = 0.f; }

  for (int jt = 0; jt < 8; ++jt) {
    long j0 = (long)jc * 1024 + jt * 128;
#pragma unroll
    for (int it = 0; it < 4; ++it) {
      int q = it * 256 + tid;
      int row = q >> 3, c8 = q & 7;
      load16(Kp + (j0 + row) * 64 + c8 * 8, &Kt[q * 8]);
    }
    __syncthreads();
    f32x4 acc[2][8] = {};
#pragma unroll
    for (int kk = 0; kk < 64; kk += 32) {
      s16x8 af[2], bf[8];
#pragma unroll
      for (int i = 0; i < 2; ++i)
        af[i] = *(const s16x8*)&Qt[(w * 32 + i * 16 + l15) * 64 + kk + lhi * 8];
#pragma unroll
      for (int j = 0; j < 8; ++j)
        bf[j] = *(const s16x8*)&Kt[(j * 16 + l15) * 64 + kk + lhi * 8];
#pragma unroll
      for (int i = 0; i < 2; ++i)
#pragma unroll
        for (int j = 0; j < 8; ++j)
          acc[i][j] = __builtin_amdgcn_mfma_f32_16x16x32_bf16(af[i], bf[j],
                                                              acc[i][j], 0, 0, 0);
    }
#pragma unroll
    for (int i = 0; i < 2; ++i)
#pragma unroll
      for (int r = 0; r < 4; ++r) {
        float tm = acc[i][0][r];
#pragma unroll
        for (int j = 1; j < 8; ++j) tm = fmaxf(tm, acc[i][j][r]);
        float mo = mrun[i][r];
        float mn = fmaxf(mo, tm);
        float s = 0.f;
#pragma unroll
        for (int j = 0; j < 8; ++j) s += __expf(acc[i][j][r] - mn);
        lrun[i][r] = lrun[i][r] * __expf(mo - mn) + s;
        mrun[i][r] = mn;
      }
    __syncthreads();
  }

#pragma unroll
  for (int i = 0; i < 2; ++i)
#pragma unroll
    for (int r = 0; r < 4; ++r) {
      float m = mrun[i][r], l = lrun[i][r];
#pragma unroll
      for (int d = 1; d < 16; d <<= 1) {
        float mo = __shfl_xor(m, d);
        float lo = __shfl_xor(l, d);
        float mn = fmaxf(m, mo);
        l = l * __expf(m - mn) + lo * __expf(mo - mn);
        m = mn;
      }
      if (l15 == 0) {
        long ig = i0 + w * 32 + i * 16 + lhi * 4 + r;
        long idx = ((long)(b * 4 + jc)) * 4096 + ig;
        m_part[idx] = m;
        l_part[idx] = l;
      }
    }
}

__global__ __launch_bounds__(256) void merge_k(const float* __restrict__ m_part,
                                               const float* __restrict__ l_part,
                                               float* __restrict__ mfin,
                                               float* __restrict__ linv) {
  int idx = blockIdx.x * 256 + threadIdx.x;  // 8*4096
  int b = idx >> 12, i = idx & 4095;
  float m = -1e30f, l = 0.f;
#pragma unroll
  for (int jc = 0; jc < 4; ++jc) {
    long o = ((long)(b * 4 + jc)) * 4096 + i;
    float mp = m_part[o], lp = l_part[o];
    float mn = fmaxf(m, mp);
    l = l * __expf(m - mn) + lp * __expf(mp - mn);
    m = mn;
  }
  mfin[idx] = m;
  linv[idx] = 1.0f / l;
}

// ---------------- host ----------------

extern "C" void kernel_launch(void* const* d_in, const int* in_sizes, int n_in,
                              void* d_out, int out_size, void* d_ws,
                              size_t ws_size, hipStream_t stream) {
  const float* x = (const float*)d_in[0];
  const float* Wq = (const float*)d_in[1];
  const float* bq = (const float*)d_in[2];
  const float* Wk = (const float*)d_in[3];
  const float* bk = (const float*)d_in[4];
  const float* Wv = (const float*)d_in[5];
  const float* bv = (const float*)d_in[6];
  const float* gamma = (const float*)d_in[7];
  float* out = (float*)d_out;

  char* ws = (char*)d_ws;
  size_t off = 0;
  auto alloc = [&](size_t bytes) {
    char* p = ws + off;
    off += (bytes + 255) & ~(size_t)255;
    return p;
  };
  u16* xb = (u16*)alloc((size_t)32768 * 512 * 2);        // 32 MB
  u16* Wcat = (u16*)alloc((size_t)640 * 512 * 2);        // 640 KB
  u16* Qb = (u16*)alloc((size_t)8 * 4096 * 64 * 2);      // 4 MB
  u16* Kb = (u16*)alloc((size_t)8 * 4096 * 64 * 2);      // 4 MB
  u16* Vr = (u16*)alloc((size_t)8 * 4096 * 512 * 2);     // 32 MB
  u16* Vt = (u16*)alloc((size_t)8 * 512 * 4096 * 2);     // 32 MB
  float* m_part = (float*)alloc((size_t)8 * 4 * 4096 * 4);
  float* l_part = (float*)alloc((size_t)8 * 4 * 4096 * 4);
  float* mfin = (float*)alloc((size_t)8 * 4096 * 4);
  float* lnv = (float*)alloc((size_t)8 * 4096 * 4);
  // Pt reused across 2 groups of 4 batches (stream order serializes reuse)
  u16* Pt = (u16*)alloc((size_t)4 * 4096 * 4096 * 2);    // 128 MB
  if (off > ws_size) {
    fprintf(stderr, "kernel_launch: ws too small: need %zu have %zu\n", off,
            ws_size);
    return;
  }

  // 1-2) dtype conversions
  cvt_w_k<<<1280, 256, 0, stream>>>(Wq, Wk, Wv, Wcat);
  cvt_x_k<<<16384, 256, 0, stream>>>(x, xb);
  // 3) fused q/k/v projection GEMM  (M=32768, N=640, K=512)
  gemmT<128, 128, 0><<<dim3(256, 5, 1), 256, 0, stream>>>(
      xb, Wcat, 512, 512, 512, 0, 0, Qb, Kb, Vr, (void*)bq, (void*)bk,
      (void*)bv, 0, 0, 0);
  // 4) transpose V
  transV_k<<<dim3(64, 8, 8), 256, 0, stream>>>(Vr, Vt);
  // 5) softmax row stats (recompute S)
  stats_k<<<dim3(32, 4, 8), 256, 0, stream>>>(Qb, Kb, m_part, l_part);
  merge_k<<<128, 256, 0, stream>>>(m_part, l_part, mfin, lnv);
  // 6/7) per 4-batch group: P^T materialization then PV GEMM + epilogue
  for (int g = 0; g < 2; ++g) {
    long bo = (long)g * 4;
    gemmT<128, 128, 1><<<dim3(32, 32, 4), 256, 0, stream>>>(
        Kb + bo * 4096 * 64, Qb + bo * 4096 * 64, 64, 64, 64,
        (long)4096 * 64, (long)4096 * 64, Pt, mfin + bo * 4096,
        lnv + bo * 4096, nullptr, nullptr, nullptr, (long)4096 * 4096 * 2,
        (long)4096 * 4, (long)4096 * 4);
    gemmT<128, 256, 2><<<dim3(32, 2, 4), 256, 0, stream>>>(
        Pt, Vt + bo * 512 * 4096, 4096, 4096, 4096, (long)4096 * 4096,
        (long)512 * 4096, out + bo * 4096 * 512,
        (void*)(x + bo * 4096 * 512), (void*)gamma, nullptr, nullptr,
        nullptr, (long)4096 * 512 * 4, (long)4096 * 512 * 4, 0);
  }
}

// Round 3
// 325.582 us; speedup vs baseline: 1.6716x; 1.6716x over previous
//
#include <hip/hip_runtime.h>
#include <hip/hip_bf16.h>
#include <cstdio>

typedef unsigned short u16;
typedef __attribute__((ext_vector_type(4))) float f32x4;
typedef __attribute__((ext_vector_type(8))) short s16x8;

__device__ __forceinline__ u16 bf16b(float f) {
  union { float f; unsigned u; } c; c.f = f;
  unsigned u = c.u;
  return (u16)((u + 0x7FFFu + ((u >> 16) & 1u)) >> 16);
}

__device__ __forceinline__ void load16(const void* g, void* l) {
  __builtin_amdgcn_global_load_lds(
      (const __attribute__((address_space(1))) void*)g,
      (__attribute__((address_space(3))) void*)l, 16, 0, 0);
}

// ---------------- converters ----------------

__global__ __launch_bounds__(256) void cvt_x_k(const float* __restrict__ x,
                                               u16* __restrict__ xb) {
  long i = ((long)blockIdx.x * 256 + threadIdx.x) * 4;
  float4 f = *(const float4*)&x[i];
  unsigned lo = (unsigned)bf16b(f.x) | ((unsigned)bf16b(f.y) << 16);
  unsigned hi = (unsigned)bf16b(f.z) | ((unsigned)bf16b(f.w) << 16);
  uint2 v; v.x = lo; v.y = hi;
  *(uint2*)&xb[i] = v;
}

__global__ __launch_bounds__(256) void cvt_w_k(const float* __restrict__ Wq,
                                               const float* __restrict__ Wk,
                                               const float* __restrict__ Wv,
                                               u16* __restrict__ Wcat) {
  int idx = blockIdx.x * 256 + threadIdx.x;  // 640*512
  int nn = idx >> 9, k = idx & 511;
  float v;
  if (nn < 64)       v = Wq[k * 64 + nn];
  else if (nn < 128) v = Wk[k * 64 + (nn - 64)];
  else               v = Wv[k * 512 + (nn - 128)];
  Wcat[idx] = bf16b(v);
}

// Vr [b][4096][512] -> Vt [b][512][4096]
__global__ __launch_bounds__(256) void transV_k(const u16* __restrict__ Vr,
                                                u16* __restrict__ Vt) {
  __shared__ u16 t[64][66];
  const int b = blockIdx.z;
  const long i0 = (long)blockIdx.x * 64, c0 = (long)blockIdx.y * 64;
  const u16* src = Vr + (long)b * 4096 * 512;
  u16* dst = Vt + (long)b * 512 * 4096;
  const int tid = threadIdx.x;
#pragma unroll
  for (int p = 0; p < 16; ++p) {
    int idx = p * 256 + tid;
    int r = idx >> 6, c = idx & 63;
    t[r][c] = src[(i0 + r) * 512 + c0 + c];
  }
  __syncthreads();
#pragma unroll
  for (int p = 0; p < 16; ++p) {
    int idx = p * 256 + tid;
    int r = idx >> 6, c = idx & 63;
    dst[(c0 + r) * 4096 + i0 + c] = t[c][r];
  }
}

// ---------------- generic GEMM-T (used for projections only) ----------------
// C[m,n] = sum_k A[m,k]*B[n,k]; EPI 0: -> Qb/Kb/Vr bf16 + bias
template <int BM, int BN, int EPI>
__global__ __launch_bounds__(256, 2) void gemmT(
    const u16* __restrict__ A, const u16* __restrict__ B, int K, int lda,
    int ldb, long sA, long sB, void* p0, void* p1, void* p2, void* p3,
    void* p4, void* p5, long s0, long s1, long s2) {
  constexpr int FM = BM / 32, FN = BN / 32;
  __shared__ __align__(16) u16 At[BM * 64];
  __shared__ __align__(16) u16 Bt[BN * 64];
  const int tid = threadIdx.x;
  const int lane = tid & 63, w = tid >> 6;
  const int wr = w >> 1, wc = w & 1;
  const int l15 = lane & 15, lhi = lane >> 4;
  const long m0 = (long)blockIdx.x * BM;
  const long n0 = (long)blockIdx.y * BN;
  const int z = blockIdx.z;
  A += (long)z * sA;
  B += (long)z * sB;
  char* b0 = (char*)p0 + (long)z * s0;
  char* b1 = (char*)p1 + (long)z * s1;
  char* b2 = (char*)p2 + (long)z * s2;

  f32x4 acc[FM][FN] = {};

  for (int k0 = 0; k0 < K; k0 += 64) {
#pragma unroll
    for (int it = 0; it < (BM + BN) * 8 / 256; ++it) {
      int q = it * 256 + tid;
      if (q < BM * 8) {
        int row = q >> 3, c8 = q & 7;
        load16(A + (m0 + row) * lda + k0 + c8 * 8, &At[q * 8]);
      } else {
        int q2 = q - BM * 8;
        int row = q2 >> 3, c8 = q2 & 7;
        load16(B + (n0 + row) * ldb + k0 + c8 * 8, &Bt[q2 * 8]);
      }
    }
    __syncthreads();
#pragma unroll
    for (int kk = 0; kk < 64; kk += 32) {
      s16x8 af[FM], bf[FN];
#pragma unroll
      for (int i = 0; i < FM; ++i)
        af[i] = *(const s16x8*)&At[(wr * (BM / 2) + i * 16 + l15) * 64 + kk + lhi * 8];
#pragma unroll
      for (int j = 0; j < FN; ++j)
        bf[j] = *(const s16x8*)&Bt[(wc * (BN / 2) + j * 16 + l15) * 64 + kk + lhi * 8];
#pragma unroll
      for (int i = 0; i < FM; ++i)
#pragma unroll
        for (int j = 0; j < FN; ++j)
          acc[i][j] = __builtin_amdgcn_mfma_f32_16x16x32_bf16(af[i], bf[j],
                                                              acc[i][j], 0, 0, 0);
    }
    __syncthreads();
  }

#pragma unroll
  for (int i = 0; i < FM; ++i) {
#pragma unroll
    for (int j = 0; j < FN; ++j) {
      long mm = m0 + wr * (BM / 2) + i * 16 + lhi * 4;
      long nn = n0 + wc * (BN / 2) + j * 16 + l15;
#pragma unroll
      for (int r = 0; r < 4; ++r) {
        long m = mm + r;
        float v = acc[i][j][r];
        if constexpr (EPI == 0) {
          if (nn < 64) {
            v += ((const float*)p3)[nn];
            ((u16*)b0)[m * 64 + nn] = bf16b(v);
          } else if (nn < 128) {
            v += ((const float*)p4)[nn - 64];
            ((u16*)b1)[m * 64 + nn - 64] = bf16b(v);
          } else {
            v += ((const float*)p5)[nn - 128];
            ((u16*)b2)[m * 512 + nn - 128] = bf16b(v);
          }
        }
      }
    }
  }
}

// ---------------- softmax row stats (over j) via S recompute ----------------
__global__ __launch_bounds__(256, 2) void stats_k(const u16* __restrict__ Qb,
                                                  const u16* __restrict__ Kb,
                                                  float* __restrict__ m_part,
                                                  float* __restrict__ l_part) {
  const int b = blockIdx.z, jc = blockIdx.y;
  const long i0 = (long)blockIdx.x * 128;
  const u16* Q = Qb + (long)b * 4096 * 64;
  const u16* Kp = Kb + (long)b * 4096 * 64;
  __shared__ __align__(16) u16 Qt[128 * 64];
  __shared__ __align__(16) u16 Kt[128 * 64];
  const int tid = threadIdx.x, lane = tid & 63, w = tid >> 6;
  const int l15 = lane & 15, lhi = lane >> 4;

#pragma unroll
  for (int it = 0; it < 4; ++it) {
    int q = it * 256 + tid;
    int row = q >> 3, c8 = q & 7;
    load16(Q + (i0 + row) * 64 + c8 * 8, &Qt[q * 8]);
  }

  float mrun[2][4], lrun[2][4];
#pragma unroll
  for (int i = 0; i < 2; ++i)
#pragma unroll
    for (int r = 0; r < 4; ++r) { mrun[i][r] = -1e30f; lrun[i][r] = 0.f; }

  for (int jt = 0; jt < 8; ++jt) {
    long j0 = (long)jc * 1024 + jt * 128;
#pragma unroll
    for (int it = 0; it < 4; ++it) {
      int q = it * 256 + tid;
      int row = q >> 3, c8 = q & 7;
      load16(Kp + (j0 + row) * 64 + c8 * 8, &Kt[q * 8]);
    }
    __syncthreads();
    f32x4 acc[2][8] = {};
#pragma unroll
    for (int kk = 0; kk < 64; kk += 32) {
      s16x8 af[2], bf[8];
#pragma unroll
      for (int i = 0; i < 2; ++i)
        af[i] = *(const s16x8*)&Qt[(w * 32 + i * 16 + l15) * 64 + kk + lhi * 8];
#pragma unroll
      for (int j = 0; j < 8; ++j)
        bf[j] = *(const s16x8*)&Kt[(j * 16 + l15) * 64 + kk + lhi * 8];
#pragma unroll
      for (int i = 0; i < 2; ++i)
#pragma unroll
        for (int j = 0; j < 8; ++j)
          acc[i][j] = __builtin_amdgcn_mfma_f32_16x16x32_bf16(af[i], bf[j],
                                                              acc[i][j], 0, 0, 0);
    }
#pragma unroll
    for (int i = 0; i < 2; ++i)
#pragma unroll
      for (int r = 0; r < 4; ++r) {
        float tm = acc[i][0][r];
#pragma unroll
        for (int j = 1; j < 8; ++j) tm = fmaxf(tm, acc[i][j][r]);
        float mo = mrun[i][r];
        float mn = fmaxf(mo, tm);
        float s = 0.f;
#pragma unroll
        for (int j = 0; j < 8; ++j) s += __expf(acc[i][j][r] - mn);
        lrun[i][r] = lrun[i][r] * __expf(mo - mn) + s;
        mrun[i][r] = mn;
      }
    __syncthreads();
  }

#pragma unroll
  for (int i = 0; i < 2; ++i)
#pragma unroll
    for (int r = 0; r < 4; ++r) {
      float m = mrun[i][r], l = lrun[i][r];
#pragma unroll
      for (int d = 1; d < 16; d <<= 1) {
        float mo = __shfl_xor(m, d);
        float lo = __shfl_xor(l, d);
        float mn = fmaxf(m, mo);
        l = l * __expf(m - mn) + lo * __expf(mo - mn);
        m = mn;
      }
      if (l15 == 0) {
        long ig = i0 + w * 32 + i * 16 + lhi * 4 + r;
        long idx = ((long)(b * 4 + jc)) * 4096 + ig;
        m_part[idx] = m;
        l_part[idx] = l;
      }
    }
}

__global__ __launch_bounds__(256) void merge_k(const float* __restrict__ m_part,
                                               const float* __restrict__ l_part,
                                               float* __restrict__ mfin,
                                               float* __restrict__ linv) {
  int idx = blockIdx.x * 256 + threadIdx.x;  // 8*4096
  int b = idx >> 12, i = idx & 4095;
  float m = -1e30f, l = 0.f;
#pragma unroll
  for (int jc = 0; jc < 4; ++jc) {
    long o = ((long)(b * 4 + jc)) * 4096 + i;
    float mp = m_part[o], lp = l_part[o];
    float mn = fmaxf(m, mp);
    l = l * __expf(m - mn) + lp * __expf(mp - mn);
    m = mn;
  }
  mfin[idx] = m;
  linv[idx] = 1.0f / l;
}

// ---------------- fused P·V (flash-style, second pass) ----------------
// Block: out[b, j0:j0+128, c0:c0+256]. Loop i in 64-chunks:
//   GEMM1: S[i][j] = Q_chunk · K_tile^T  (A=Q so D has j in lane&15)
//   epi:   p = exp(s - m_i) * linv_i  -> bf16 -> swizzled LDS Pl[j][i]
//   GEMM2: acc += Pl(as A) · Vc(as B)
// All LDS tiles XOR-swizzled: byte ^= (row&7)<<4 (staged via pre-swz source).
__global__ __launch_bounds__(256, 2) void fusedPV(
    const u16* __restrict__ Qb, const u16* __restrict__ Kb,
    const u16* __restrict__ Vt, const float* __restrict__ mfin,
    const float* __restrict__ lnv, const float* __restrict__ x,
    const float* __restrict__ gamma, float* __restrict__ out) {
  __shared__ __align__(16) u16 Kt[128 * 64];
  __shared__ __align__(16) u16 Qc[64 * 64];
  __shared__ __align__(16) u16 Vc[256 * 64];
  __shared__ __align__(16) u16 Pl[128 * 64];
  __shared__ __align__(16) float Ml[64];
  __shared__ __align__(16) float Ll[64];
  const int tid = threadIdx.x, lane = tid & 63, w = tid >> 6;
  const int l15 = lane & 15, lhi = lane >> 4;
  const int wi = w & 1, wj = w >> 1, wc = w & 1;
  const int b = blockIdx.z;
  const long j0 = (long)blockIdx.x * 128;
  const long c0 = (long)blockIdx.y * 256;
  const u16* Qg = Qb + (long)b * 4096 * 64;
  const u16* Kg = Kb + (long)b * 4096 * 64;
  const u16* Vg = Vt + (long)b * 512 * 4096;
  const float* mg = mfin + (long)b * 4096;
  const float* lg = lnv + (long)b * 4096;

  // stage K tile once (loop-invariant): 128 rows x 128B
#pragma unroll
  for (int p = 0; p < 4; ++p) {
    int s = p * 256 + tid;
    int r = s >> 3, col = s & 7, cg = col ^ (r & 7);
    load16(Kg + (j0 + r) * 64 + cg * 8, (char*)Kt + r * 128 + col * 16);
  }

  f32x4 acc2[4][8] = {};
  const float gma = gamma[0];

  for (int t = 0; t < 64; ++t) {
    const int i_base = t * 64;
    // stage Q chunk (64 x 128B)
#pragma unroll
    for (int p = 0; p < 2; ++p) {
      int s = p * 256 + tid;
      int r = s >> 3, col = s & 7, cg = col ^ (r & 7);
      load16(Qg + (long)(i_base + r) * 64 + cg * 8,
             (char*)Qc + r * 128 + col * 16);
    }
    // stage V chunk (256 c-rows x 128B)
#pragma unroll
    for (int p = 0; p < 8; ++p) {
      int s = p * 256 + tid;
      int r = s >> 3, col = s & 7, cg = col ^ (r & 7);
      load16(Vg + (c0 + r) * 4096 + i_base + cg * 8,
             (char*)Vc + r * 128 + col * 16);
    }
    if (tid < 64) {
      Ml[tid] = mg[i_base + tid];
      Ll[tid] = lg[i_base + tid];
    }
    __syncthreads();

    // GEMM1: S[i(64)][j(128)]; wave (wi,wj): 32i x 64j; acc1[fi 2][fj 4]
    f32x4 acc1[2][4] = {};
#pragma unroll
    for (int kk = 0; kk < 64; kk += 32) {
      s16x8 af[2], bk4[4];
#pragma unroll
      for (int fi = 0; fi < 2; ++fi) {
        int r = wi * 32 + fi * 16 + l15;
        af[fi] = *(const s16x8*)((const char*)Qc + r * 128 +
                                 (((kk + lhi * 8) * 2) ^ ((r & 7) << 4)));
      }
#pragma unroll
      for (int fj = 0; fj < 4; ++fj) {
        int r = wj * 64 + fj * 16 + l15;
        bk4[fj] = *(const s16x8*)((const char*)Kt + r * 128 +
                                  (((kk + lhi * 8) * 2) ^ ((r & 7) << 4)));
      }
#pragma unroll
      for (int fi = 0; fi < 2; ++fi)
#pragma unroll
        for (int fj = 0; fj < 4; ++fj)
          acc1[fi][fj] = __builtin_amdgcn_mfma_f32_16x16x32_bf16(
              af[fi], bk4[fj], acc1[fi][fj], 0, 0, 0);
    }

    // epilogue: p = exp(s - m_i)*linv_i -> bf16 -> Pl[j][i] (swizzled)
#pragma unroll
    for (int fi = 0; fi < 2; ++fi) {
      int i0l = wi * 32 + fi * 16 + lhi * 4;
      f32x4 mv = *(const f32x4*)&Ml[i0l];
      f32x4 lv = *(const f32x4*)&Ll[i0l];
#pragma unroll
      for (int fj = 0; fj < 4; ++fj) {
        int j = wj * 64 + fj * 16 + l15;
        float p0 = __expf(acc1[fi][fj][0] - mv[0]) * lv[0];
        float p1 = __expf(acc1[fi][fj][1] - mv[1]) * lv[1];
        float p2 = __expf(acc1[fi][fj][2] - mv[2]) * lv[2];
        float p3 = __expf(acc1[fi][fj][3] - mv[3]) * lv[3];
        unsigned u01 = (unsigned)bf16b(p0) | ((unsigned)bf16b(p1) << 16);
        unsigned u23 = (unsigned)bf16b(p2) | ((unsigned)bf16b(p3) << 16);
        char* base = (char*)Pl + j * 128;
        int byt = (i0l * 2) ^ ((j & 7) << 4);
        *(unsigned*)(base + byt) = u01;
        *(unsigned*)(base + byt + 4) = u23;
      }
    }
    __syncthreads();

    // GEMM2: acc2 += Pl^T-as-A (m=j, k=i) x Vc-as-B (n=c, k=i)
#pragma unroll
    for (int kk = 0; kk < 64; kk += 32) {
      s16x8 pa[4];
#pragma unroll
      for (int fm = 0; fm < 4; ++fm) {
        int r = wj * 64 + fm * 16 + l15;
        pa[fm] = *(const s16x8*)((const char*)Pl + r * 128 +
                                 (((kk + lhi * 8) * 2) ^ ((r & 7) << 4)));
      }
#pragma unroll
      for (int fn = 0; fn < 8; ++fn) {
        int r = wc * 128 + fn * 16 + l15;
        s16x8 vb = *(const s16x8*)((const char*)Vc + r * 128 +
                                   (((kk + lhi * 8) * 2) ^ ((r & 7) << 4)));
#pragma unroll
        for (int fm = 0; fm < 4; ++fm)
          acc2[fm][fn] = __builtin_amdgcn_mfma_f32_16x16x32_bf16(
              pa[fm], vb, acc2[fm][fn], 0, 0, 0);
      }
    }
    __syncthreads();
  }

  // final epilogue: out = gamma*acc2 + x
#pragma unroll
  for (int fm = 0; fm < 4; ++fm) {
#pragma unroll
    for (int fn = 0; fn < 8; ++fn) {
      long j = j0 + wj * 64 + fm * 16 + lhi * 4;
      long c = c0 + wc * 128 + fn * 16 + l15;
#pragma unroll
      for (int r = 0; r < 4; ++r) {
        long o = ((long)b * 4096 + j + r) * 512 + c;
        out[o] = gma * acc2[fm][fn][r] + x[o];
      }
    }
  }
}

// ---------------- host ----------------

extern "C" void kernel_launch(void* const* d_in, const int* in_sizes, int n_in,
                              void* d_out, int out_size, void* d_ws,
                              size_t ws_size, hipStream_t stream) {
  const float* x = (const float*)d_in[0];
  const float* Wq = (const float*)d_in[1];
  const float* bq = (const float*)d_in[2];
  const float* Wk = (const float*)d_in[3];
  const float* bk = (const float*)d_in[4];
  const float* Wv = (const float*)d_in[5];
  const float* bv = (const float*)d_in[6];
  const float* gamma = (const float*)d_in[7];
  float* out = (float*)d_out;

  char* ws = (char*)d_ws;
  size_t off = 0;
  auto alloc = [&](size_t bytes) {
    char* p = ws + off;
    off += (bytes + 255) & ~(size_t)255;
    return p;
  };
  u16* xb = (u16*)alloc((size_t)32768 * 512 * 2);        // 32 MB
  u16* Wcat = (u16*)alloc((size_t)640 * 512 * 2);        // 640 KB
  u16* Qb = (u16*)alloc((size_t)8 * 4096 * 64 * 2);      // 4 MB
  u16* Kb = (u16*)alloc((size_t)8 * 4096 * 64 * 2);      // 4 MB
  u16* Vr = (u16*)alloc((size_t)8 * 4096 * 512 * 2);     // 32 MB
  u16* Vt = (u16*)alloc((size_t)8 * 512 * 4096 * 2);     // 32 MB
  float* m_part = (float*)alloc((size_t)8 * 4 * 4096 * 4);
  float* l_part = (float*)alloc((size_t)8 * 4 * 4096 * 4);
  float* mfin = (float*)alloc((size_t)8 * 4096 * 4);
  float* lnv = (float*)alloc((size_t)8 * 4096 * 4);
  if (off > ws_size) {
    fprintf(stderr, "kernel_launch: ws too small: need %zu have %zu\n", off,
            ws_size);
    return;
  }

  // 1-2) dtype conversions
  cvt_w_k<<<1280, 256, 0, stream>>>(Wq, Wk, Wv, Wcat);
  cvt_x_k<<<16384, 256, 0, stream>>>(x, xb);
  // 3) fused q/k/v projection GEMM  (M=32768, N=640, K=512)
  gemmT<128, 128, 0><<<dim3(256, 5, 1), 256, 0, stream>>>(
      xb, Wcat, 512, 512, 512, 0, 0, Qb, Kb, Vr, (void*)bq, (void*)bk,
      (void*)bv, 0, 0, 0);
  // 4) transpose V
  transV_k<<<dim3(64, 8, 8), 256, 0, stream>>>(Vr, Vt);
  // 5) softmax row stats (recompute S)
  stats_k<<<dim3(32, 4, 8), 256, 0, stream>>>(Qb, Kb, m_part, l_part);
  merge_k<<<128, 256, 0, stream>>>(m_part, l_part, mfin, lnv);
  // 6) fused P recompute + P·V + residual epilogue (all 8 batches)
  fusedPV<<<dim3(32, 2, 8), 256, 0, stream>>>(Qb, Kb, Vt, mfin, lnv, x,
                                              gamma, out);
}

// Round 4
// 314.361 us; speedup vs baseline: 1.7313x; 1.0357x over previous
//
#include <hip/hip_runtime.h>
#include <hip/hip_bf16.h>
#include <cstdio>

typedef unsigned short u16;
typedef __attribute__((ext_vector_type(4))) float f32x4;
typedef __attribute__((ext_vector_type(8))) short s16x8;

__device__ __forceinline__ u16 bf16b(float f) {
  union { float f; unsigned u; } c; c.f = f;
  unsigned u = c.u;
  return (u16)((u + 0x7FFFu + ((u >> 16) & 1u)) >> 16);
}

__device__ __forceinline__ void load16(const void* g, void* l) {
  __builtin_amdgcn_global_load_lds(
      (const __attribute__((address_space(1))) void*)g,
      (__attribute__((address_space(3))) void*)l, 16, 0, 0);
}

// full drain + barrier (used once per iter; prefetched loads were issued a
// full iteration earlier so the vmcnt(0) is nearly free)
#define BARV() asm volatile("s_waitcnt vmcnt(0) lgkmcnt(0)\n\ts_barrier" ::: "memory")
// lgkmcnt-only barrier: prefetch global_load_lds stay IN FLIGHT across it
#define BAR() asm volatile("s_waitcnt lgkmcnt(0)\n\ts_barrier" ::: "memory")

// ---------------- converters ----------------

__global__ __launch_bounds__(256) void cvt_x_k(const float* __restrict__ x,
                                               u16* __restrict__ xb) {
  long i = ((long)blockIdx.x * 256 + threadIdx.x) * 4;
  float4 f = *(const float4*)&x[i];
  unsigned lo = (unsigned)bf16b(f.x) | ((unsigned)bf16b(f.y) << 16);
  unsigned hi = (unsigned)bf16b(f.z) | ((unsigned)bf16b(f.w) << 16);
  uint2 v; v.x = lo; v.y = hi;
  *(uint2*)&xb[i] = v;
}

__global__ __launch_bounds__(256) void cvt_w_k(const float* __restrict__ Wq,
                                               const float* __restrict__ Wk,
                                               const float* __restrict__ Wv,
                                               u16* __restrict__ Wcat) {
  int idx = blockIdx.x * 256 + threadIdx.x;  // 640*512
  int nn = idx >> 9, k = idx & 511;
  float v;
  if (nn < 64)       v = Wq[k * 64 + nn];
  else if (nn < 128) v = Wk[k * 64 + (nn - 64)];
  else               v = Wv[k * 512 + (nn - 128)];
  Wcat[idx] = bf16b(v);
}

// ---------------- projection GEMM: C[m,n] = sum_k A[m,k]*B[n,k] ----------------
// writes Qb/Kb bf16 row-major and Vt TRANSPOSED ([b][c][n]) directly.
__global__ __launch_bounds__(256, 2) void projGemm(
    const u16* __restrict__ A, const u16* __restrict__ B,
    u16* __restrict__ Qb, u16* __restrict__ Kb, u16* __restrict__ Vt,
    const float* __restrict__ bq, const float* __restrict__ bk,
    const float* __restrict__ bv) {
  constexpr int BM = 128, BN = 128, FM = 4, FN = 4;
  __shared__ __align__(16) u16 At[BM * 64];
  __shared__ __align__(16) u16 Bt[BN * 64];
  const int tid = threadIdx.x;
  const int lane = tid & 63, w = tid >> 6;
  const int wr = w >> 1, wc = w & 1;
  const int l15 = lane & 15, lhi = lane >> 4;
  const long m0 = (long)blockIdx.x * BM;
  const long n0 = (long)blockIdx.y * BN;

  f32x4 acc[FM][FN] = {};

  for (int k0 = 0; k0 < 512; k0 += 64) {
#pragma unroll
    for (int it = 0; it < 8; ++it) {
      int q = it * 256 + tid;
      if (q < BM * 8) {
        int row = q >> 3, c8 = q & 7;
        load16(A + (m0 + row) * 512 + k0 + c8 * 8, &At[q * 8]);
      } else {
        int q2 = q - BM * 8;
        int row = q2 >> 3, c8 = q2 & 7;
        load16(B + (n0 + row) * 512 + k0 + c8 * 8, &Bt[q2 * 8]);
      }
    }
    __syncthreads();
#pragma unroll
    for (int kk = 0; kk < 64; kk += 32) {
      s16x8 af[FM], bf[FN];
#pragma unroll
      for (int i = 0; i < FM; ++i)
        af[i] = *(const s16x8*)&At[(wr * 64 + i * 16 + l15) * 64 + kk + lhi * 8];
#pragma unroll
      for (int j = 0; j < FN; ++j)
        bf[j] = *(const s16x8*)&Bt[(wc * 64 + j * 16 + l15) * 64 + kk + lhi * 8];
#pragma unroll
      for (int i = 0; i < FM; ++i)
#pragma unroll
        for (int j = 0; j < FN; ++j)
          acc[i][j] = __builtin_amdgcn_mfma_f32_16x16x32_bf16(af[i], bf[j],
                                                              acc[i][j], 0, 0, 0);
    }
    __syncthreads();
  }

#pragma unroll
  for (int i = 0; i < FM; ++i) {
#pragma unroll
    for (int j = 0; j < FN; ++j) {
      long mm = m0 + wr * 64 + i * 16 + lhi * 4;
      long nn = n0 + wc * 64 + j * 16 + l15;
      if (nn < 64) {
        float bb = bq[nn];
#pragma unroll
        for (int r = 0; r < 4; ++r)
          Qb[(mm + r) * 64 + nn] = bf16b(acc[i][j][r] + bb);
      } else if (nn < 128) {
        float bb = bk[nn - 64];
#pragma unroll
        for (int r = 0; r < 4; ++r)
          Kb[(mm + r) * 64 + nn - 64] = bf16b(acc[i][j][r] + bb);
      } else {
        long c = nn - 128;
        float bb = bv[c];
        unsigned u01 = (unsigned)bf16b(acc[i][j][0] + bb) |
                       ((unsigned)bf16b(acc[i][j][1] + bb) << 16);
        unsigned u23 = (unsigned)bf16b(acc[i][j][2] + bb) |
                       ((unsigned)bf16b(acc[i][j][3] + bb) << 16);
        uint2 u; u.x = u01; u.y = u23;
        *(uint2*)&Vt[(mm >> 12) * 512 * 4096 + c * 4096 + (mm & 4095)] = u;
      }
    }
  }
}

// ---------------- softmax row stats (over j) via S recompute ----------------
__global__ __launch_bounds__(256, 2) void stats_k(const u16* __restrict__ Qb,
                                                  const u16* __restrict__ Kb,
                                                  float* __restrict__ m_part,
                                                  float* __restrict__ l_part) {
  const int b = blockIdx.z, jc = blockIdx.y;
  const long i0 = (long)blockIdx.x * 128;
  const u16* Q = Qb + (long)b * 4096 * 64;
  const u16* Kp = Kb + (long)b * 4096 * 64;
  __shared__ __align__(16) u16 Qt[128 * 64];
  __shared__ __align__(16) u16 Kt[128 * 64];
  const int tid = threadIdx.x, lane = tid & 63, w = tid >> 6;
  const int l15 = lane & 15, lhi = lane >> 4;

#pragma unroll
  for (int it = 0; it < 4; ++it) {
    int q = it * 256 + tid;
    int row = q >> 3, c8 = q & 7;
    load16(Q + (i0 + row) * 64 + c8 * 8, &Qt[q * 8]);
  }

  float mrun[2][4], lrun[2][4];
#pragma unroll
  for (int i = 0; i < 2; ++i)
#pragma unroll
    for (int r = 0; r < 4; ++r) { mrun[i][r] = -1e30f; lrun[i][r] = 0.f; }

  for (int jt = 0; jt < 8; ++jt) {
    long j0 = (long)jc * 1024 + jt * 128;
#pragma unroll
    for (int it = 0; it < 4; ++it) {
      int q = it * 256 + tid;
      int row = q >> 3, c8 = q & 7;
      load16(Kp + (j0 + row) * 64 + c8 * 8, &Kt[q * 8]);
    }
    __syncthreads();
    f32x4 acc[2][8] = {};
#pragma unroll
    for (int kk = 0; kk < 64; kk += 32) {
      s16x8 af[2], bf[8];
#pragma unroll
      for (int i = 0; i < 2; ++i)
        af[i] = *(const s16x8*)&Qt[(w * 32 + i * 16 + l15) * 64 + kk + lhi * 8];
#pragma unroll
      for (int j = 0; j < 8; ++j)
        bf[j] = *(const s16x8*)&Kt[(j * 16 + l15) * 64 + kk + lhi * 8];
#pragma unroll
      for (int i = 0; i < 2; ++i)
#pragma unroll
        for (int j = 0; j < 8; ++j)
          acc[i][j] = __builtin_amdgcn_mfma_f32_16x16x32_bf16(af[i], bf[j],
                                                              acc[i][j], 0, 0, 0);
    }
#pragma unroll
    for (int i = 0; i < 2; ++i)
#pragma unroll
      for (int r = 0; r < 4; ++r) {
        float tm = acc[i][0][r];
#pragma unroll
        for (int j = 1; j < 8; ++j) tm = fmaxf(tm, acc[i][j][r]);
        float mo = mrun[i][r];
        float mn = fmaxf(mo, tm);
        float s = 0.f;
#pragma unroll
        for (int j = 0; j < 8; ++j) s += __expf(acc[i][j][r] - mn);
        lrun[i][r] = lrun[i][r] * __expf(mo - mn) + s;
        mrun[i][r] = mn;
      }
    __syncthreads();
  }

#pragma unroll
  for (int i = 0; i < 2; ++i)
#pragma unroll
    for (int r = 0; r < 4; ++r) {
      float m = mrun[i][r], l = lrun[i][r];
#pragma unroll
      for (int d = 1; d < 16; d <<= 1) {
        float mo = __shfl_xor(m, d);
        float lo = __shfl_xor(l, d);
        float mn = fmaxf(m, mo);
        l = l * __expf(m - mn) + lo * __expf(mo - mn);
        m = mn;
      }
      if (l15 == 0) {
        long ig = i0 + w * 32 + i * 16 + lhi * 4 + r;
        long idx = ((long)(b * 4 + jc)) * 4096 + ig;
        m_part[idx] = m;
        l_part[idx] = l;
      }
    }
}

__global__ __launch_bounds__(256) void merge_k(const float* __restrict__ m_part,
                                               const float* __restrict__ l_part,
                                               float* __restrict__ mfin,
                                               float* __restrict__ linv) {
  int idx = blockIdx.x * 256 + threadIdx.x;  // 8*4096
  int b = idx >> 12, i = idx & 4095;
  float m = -1e30f, l = 0.f;
#pragma unroll
  for (int jc = 0; jc < 4; ++jc) {
    long o = ((long)(b * 4 + jc)) * 4096 + i;
    float mp = m_part[o], lp = l_part[o];
    float mn = fmaxf(m, mp);
    l = l * __expf(m - mn) + lp * __expf(mp - mn);
    m = mn;
  }
  mfin[idx] = m;
  linv[idx] = 1.0f / l;
}

// ---------------- fused P·V, 8-wave, double-buffered ----------------
// Block: out[b, j0:j0+256, c0:c0+256]. Loop i in 64-chunks (dbuf Q/V):
//   BARV (drain prev prefetch) -> issue t+1 loads -> GEMM1 -> P epi -> BAR
//   (lgkm only; prefetch stays in flight) -> GEMM2.
__global__ __launch_bounds__(512, 2) void fusedPV(
    const u16* __restrict__ Qb, const u16* __restrict__ Kb,
    const u16* __restrict__ Vt, const float* __restrict__ mfin,
    const float* __restrict__ lnv, const float* __restrict__ x,
    const float* __restrict__ gamma, float* __restrict__ out) {
  __shared__ __align__(16) u16 Kt[256 * 64];      // 32 KB, loop-invariant
  __shared__ __align__(16) u16 Qc[2][64 * 64];    // 16 KB dbuf
  __shared__ __align__(16) u16 Vc[2][256 * 64];   // 64 KB dbuf
  __shared__ __align__(16) u16 Pl[256 * 64];      // 32 KB
  const int tid = threadIdx.x, lane = tid & 63, w = tid >> 6;
  const int l15 = lane & 15, lhi = lane >> 4;
  const int wi = w & 1, wj = w >> 1, wc = w & 1;  // wj in 0..3
  const int b = blockIdx.z;
  const long j0 = (long)blockIdx.x * 256;
  const long c0 = (long)blockIdx.y * 256;
  const u16* Qg = Qb + (long)b * 4096 * 64;
  const u16* Kg = Kb + (long)b * 4096 * 64;
  const u16* Vg = Vt + (long)b * 512 * 4096;
  const float* mg = mfin + (long)b * 4096;
  const float* lg = lnv + (long)b * 4096;

  // stage K tile once: 256 rows x 128B (swizzled via pre-swz source)
#pragma unroll
  for (int p = 0; p < 4; ++p) {
    int s = p * 512 + tid;
    int r = s >> 3, col = s & 7, cg = col ^ (r & 7);
    load16(Kg + (j0 + r) * 64 + cg * 8, (char*)Kt + r * 128 + col * 16);
  }
  // stage Q0,V0 into buf 0
  {
    int r = tid >> 3, col = tid & 7, cg = col ^ (r & 7);
    load16(Qg + (long)r * 64 + cg * 8, (char*)&Qc[0][0] + r * 128 + col * 16);
#pragma unroll
    for (int p = 0; p < 4; ++p) {
      int s = p * 512 + tid;
      int r2 = s >> 3, c2 = s & 7, cg2 = c2 ^ (r2 & 7);
      load16(Vg + (c0 + r2) * 4096 + cg2 * 8,
             (char*)&Vc[0][0] + r2 * 128 + c2 * 16);
    }
  }

  f32x4 acc2[4][8] = {};
  const float gma = gamma[0];
  int cur = 0;

  for (int t = 0; t < 64; ++t) {
    const int i_base = t * 64;
    BARV();  // buf[cur] ready everywhere; prev GEMM2 done (buf[cur^1] free)
    // prefetch t+1 into buf[cur^1] — stays in flight through BAR/GEMM2
    if (t < 63) {
      const long ib2 = (long)(t + 1) * 64;
      int r = tid >> 3, col = tid & 7, cg = col ^ (r & 7);
      load16(Qg + (ib2 + r) * 64 + cg * 8,
             (char*)&Qc[cur ^ 1][0] + r * 128 + col * 16);
#pragma unroll
      for (int p = 0; p < 4; ++p) {
        int s = p * 512 + tid;
        int r2 = s >> 3, c2 = s & 7, cg2 = c2 ^ (r2 & 7);
        load16(Vg + (c0 + r2) * 4096 + ib2 + cg2 * 8,
               (char*)&Vc[cur ^ 1][0] + r2 * 128 + c2 * 16);
      }
    }

    // GEMM1: S[i(64)][j(256)]; wave (wi,wj): 32i x 64j
    f32x4 acc1[2][4] = {};
#pragma unroll
    for (int kk = 0; kk < 64; kk += 32) {
      s16x8 af[2], bk4[4];
#pragma unroll
      for (int fi = 0; fi < 2; ++fi) {
        int r = wi * 32 + fi * 16 + l15;
        af[fi] = *(const s16x8*)((const char*)&Qc[cur][0] + r * 128 +
                                 (((kk + lhi * 8) * 2) ^ ((r & 7) << 4)));
      }
#pragma unroll
      for (int fj = 0; fj < 4; ++fj) {
        int r = wj * 64 + fj * 16 + l15;
        bk4[fj] = *(const s16x8*)((const char*)Kt + r * 128 +
                                  (((kk + lhi * 8) * 2) ^ ((r & 7) << 4)));
      }
#pragma unroll
      for (int fi = 0; fi < 2; ++fi)
#pragma unroll
        for (int fj = 0; fj < 4; ++fj)
          acc1[fi][fj] = __builtin_amdgcn_mfma_f32_16x16x32_bf16(
              af[fi], bk4[fj], acc1[fi][fj], 0, 0, 0);
    }

    // epilogue: p = exp(s - m_i)*linv_i -> bf16 -> Pl[j][i] (swizzled)
#pragma unroll
    for (int fi = 0; fi < 2; ++fi) {
      int i0l = wi * 32 + fi * 16 + lhi * 4;
      f32x4 mv = *(const f32x4*)&mg[i_base + i0l];
      f32x4 lv = *(const f32x4*)&lg[i_base + i0l];
#pragma unroll
      for (int fj = 0; fj < 4; ++fj) {
        int j = wj * 64 + fj * 16 + l15;
        float p0 = __expf(acc1[fi][fj][0] - mv[0]) * lv[0];
        float p1 = __expf(acc1[fi][fj][1] - mv[1]) * lv[1];
        float p2 = __expf(acc1[fi][fj][2] - mv[2]) * lv[2];
        float p3 = __expf(acc1[fi][fj][3] - mv[3]) * lv[3];
        unsigned u01 = (unsigned)bf16b(p0) | ((unsigned)bf16b(p1) << 16);
        unsigned u23 = (unsigned)bf16b(p2) | ((unsigned)bf16b(p3) << 16);
        char* base = (char*)Pl + j * 128;
        int byt = (i0l * 2) ^ ((j & 7) << 4);
        *(unsigned*)(base + byt) = u01;
        *(unsigned*)(base + byt + 4) = u23;
      }
    }
    BAR();  // lgkm-only: Pl visible; prefetch loads still outstanding

    // GEMM2: acc2 += Pl(as A; m=j) x Vc(as B; n=c)
#pragma unroll
    for (int kk = 0; kk < 64; kk += 32) {
      s16x8 pa[4];
#pragma unroll
      for (int fm = 0; fm < 4; ++fm) {
        int r = wj * 64 + fm * 16 + l15;
        pa[fm] = *(const s16x8*)((const char*)Pl + r * 128 +
                                 (((kk + lhi * 8) * 2) ^ ((r & 7) << 4)));
      }
#pragma unroll
      for (int fn = 0; fn < 8; ++fn) {
        int r = wc * 128 + fn * 16 + l15;
        s16x8 vb = *(const s16x8*)((const char*)&Vc[cur][0] + r * 128 +
                                   (((kk + lhi * 8) * 2) ^ ((r & 7) << 4)));
#pragma unroll
        for (int fm = 0; fm < 4; ++fm)
          acc2[fm][fn] = __builtin_amdgcn_mfma_f32_16x16x32_bf16(
              pa[fm], vb, acc2[fm][fn], 0, 0, 0);
      }
    }
    cur ^= 1;
  }

  // final epilogue: out = gamma*acc2 + x
#pragma unroll
  for (int fm = 0; fm < 4; ++fm) {
#pragma unroll
    for (int fn = 0; fn < 8; ++fn) {
      long j = j0 + wj * 64 + fm * 16 + lhi * 4;
      long c = c0 + wc * 128 + fn * 16 + l15;
#pragma unroll
      for (int r = 0; r < 4; ++r) {
        long o = ((long)b * 4096 + j + r) * 512 + c;
        out[o] = gma * acc2[fm][fn][r] + x[o];
      }
    }
  }
}

// ---------------- host ----------------

extern "C" void kernel_launch(void* const* d_in, const int* in_sizes, int n_in,
                              void* d_out, int out_size, void* d_ws,
                              size_t ws_size, hipStream_t stream) {
  const float* x = (const float*)d_in[0];
  const float* Wq = (const float*)d_in[1];
  const float* bq = (const float*)d_in[2];
  const float* Wk = (const float*)d_in[3];
  const float* bk = (const float*)d_in[4];
  const float* Wv = (const float*)d_in[5];
  const float* bv = (const float*)d_in[6];
  const float* gamma = (const float*)d_in[7];
  float* out = (float*)d_out;

  char* ws = (char*)d_ws;
  size_t off = 0;
  auto alloc = [&](size_t bytes) {
    char* p = ws + off;
    off += (bytes + 255) & ~(size_t)255;
    return p;
  };
  u16* xb = (u16*)alloc((size_t)32768 * 512 * 2);        // 32 MB
  u16* Wcat = (u16*)alloc((size_t)640 * 512 * 2);        // 640 KB
  u16* Qb = (u16*)alloc((size_t)8 * 4096 * 64 * 2);      // 4 MB
  u16* Kb = (u16*)alloc((size_t)8 * 4096 * 64 * 2);      // 4 MB
  u16* Vt = (u16*)alloc((size_t)8 * 512 * 4096 * 2);     // 32 MB
  float* m_part = (float*)alloc((size_t)8 * 4 * 4096 * 4);
  float* l_part = (float*)alloc((size_t)8 * 4 * 4096 * 4);
  float* mfin = (float*)alloc((size_t)8 * 4096 * 4);
  float* lnv = (float*)alloc((size_t)8 * 4096 * 4);
  if (off > ws_size) {
    fprintf(stderr, "kernel_launch: ws too small: need %zu have %zu\n", off,
            ws_size);
    return;
  }

  // 1-2) dtype conversions
  cvt_w_k<<<1280, 256, 0, stream>>>(Wq, Wk, Wv, Wcat);
  cvt_x_k<<<16384, 256, 0, stream>>>(x, xb);
  // 3) fused q/k/v projection GEMM (M=32768, N=640, K=512); writes Vt directly
  projGemm<<<dim3(256, 5, 1), 256, 0, stream>>>(xb, Wcat, Qb, Kb, Vt, bq, bk,
                                                bv);
  // 4) softmax row stats (recompute S)
  stats_k<<<dim3(32, 4, 8), 256, 0, stream>>>(Qb, Kb, m_part, l_part);
  merge_k<<<128, 256, 0, stream>>>(m_part, l_part, mfin, lnv);
  // 5) fused P recompute + P·V + residual epilogue (all 8 batches)
  fusedPV<<<dim3(16, 2, 8), 512, 0, stream>>>(Qb, Kb, Vt, mfin, lnv, x,
                                              gamma, out);
}